// Round 3
// baseline (1401.793 us; speedup 1.0000x reference)
//
#include <hip/hip_runtime.h>

#define V 30000
#define E 100
#define H 100
#define T 9
#define B 256
#define S 512

__device__ __forceinline__ float fast_rcp(float x) { return __builtin_amdgcn_rcpf(x); }

// ---------------------------------------------------------------------------
// Kernel 1: P_d = embed @ Wih_d^T + b_d, PERMUTED columns:
//   P'[v][4*j + q] = P[v][q*100 + j]  (q = gate, j = unit)
// so the LSTM gather of 400 pre-activations is one coalesced 1600 B row.
// ---------------------------------------------------------------------------
#define LDE 68

__global__ __launch_bounds__(256) void precompute_P(
    const float* __restrict__ embed,
    const float* __restrict__ Wih_f, const float* __restrict__ b_f,
    const float* __restrict__ Wih_b, const float* __restrict__ b_b,
    float* __restrict__ Pf, float* __restrict__ Pb)
{
  __shared__ __align__(16) float eT[100 * LDE];
  __shared__ __align__(16) float wT[100 * LDE];
  int tid = threadIdx.x;
  int o0 = blockIdx.x * 64;
  int v0 = blockIdx.y * 64;

  for (int idx = tid; idx < 64 * 100; idx += 256) {
    int k = idx % 100, vi = idx / 100;
    int v = v0 + vi;
    eT[k * LDE + vi] = (v < V) ? embed[v * E + k] : 0.0f;
  }
  for (int idx = tid; idx < 64 * 100; idx += 256) {
    int k = idx % 100, oi = idx / 100;
    int o = o0 + oi;
    float val = 0.0f;
    if (o < 400) val = Wih_f[o * E + k];
    else if (o < 800) val = Wih_b[(o - 400) * E + k];
    wT[k * LDE + oi] = val;
  }
  __syncthreads();

  int tx = tid & 15, ty = tid >> 4;
  int vi0 = ty * 4, oi0 = tx * 4;
  float acc[4][4];
#pragma unroll
  for (int i = 0; i < 4; i++)
#pragma unroll
    for (int j = 0; j < 4; j++) acc[i][j] = 0.f;

  for (int k = 0; k < 100; k++) {
    float4 ev = *(const float4*)&eT[k * LDE + vi0];
    float4 wv = *(const float4*)&wT[k * LDE + oi0];
    float e[4] = {ev.x, ev.y, ev.z, ev.w};
    float w[4] = {wv.x, wv.y, wv.z, wv.w};
#pragma unroll
    for (int i = 0; i < 4; i++)
#pragma unroll
      for (int j = 0; j < 4; j++) acc[i][j] += e[i] * w[j];
  }

  for (int i = 0; i < 4; i++) {
    int v = v0 + vi0 + i;
    if (v >= V) break;
    for (int j = 0; j < 4; j++) {
      int o = o0 + oi0 + j;
      if (o >= 800) continue;
      int oo = (o < 400) ? o : (o - 400);
      int perm = 4 * (oo % 100) + (oo / 100);
      float bias = (o < 400) ? b_f[oo] : b_b[oo];
      float* dst = (o < 400) ? Pf : Pb;
      dst[(size_t)v * 400 + perm] = acc[i][j] + bias;
    }
  }
}

// ---------------------------------------------------------------------------
// Kernel 2: LSTM recurrence. ONE chain (dir,row) per block; 512 blocks.
// Block = 896 threads (14 waves):
//   tid in [0,800): matvec, 2 threads per output: o = tid>>1, half = tid&1.
//     K-split: half0 covers k[0,48) (13th chunk zero-padded), half1 k[48,100).
//     w stored as 26 float2 (52 VGPR); float2 accumulator -> v_pk_fma_f32.
//     Partial sums combined with shfl_xor(1); each lane activates its OWN
//     gate (q = (tid>>1)&3, 1 exp + 1 rcp), butterfly shfl_xor(2/4/6), then
//     redundant c/h update; lane (tid&7)==0 writes h.
//   tid<400 double-duty: gather next step's pre-activation row (coalesced)
//     into double-buffered pre_lds.
//   wave 13 (tid 832+): em projection with the same K-split (18 lanes).
// ONE barrier per step. em accumulated in LDS, dumped coalesced at the end.
// ---------------------------------------------------------------------------
__global__ __launch_bounds__(896, 4) void lstm_kernel(
    const int* __restrict__ x,
    const float* __restrict__ Pf, const float* __restrict__ Pb,
    const float* __restrict__ Whh_f, const float* __restrict__ Whh_b,
    const float* __restrict__ Wlin,
    float* __restrict__ em_f, float* __restrict__ em_b)
{
  __shared__ __align__(16) float h_lds[2][112];
  __shared__ __align__(16) float pre_lds[2][400];
  __shared__ int   x_lds[S];
  __shared__ float em_lds[S * T];

  int tid = threadIdx.x;
  int dir = blockIdx.x & 1;
  int b   = blockIdx.x >> 1;

  const float* P   = dir ? Pb : Pf;
  const float* Whh = dir ? Whh_b : Whh_f;
  float*       em  = dir ? em_b : em_f;

  bool is_mv = (tid < 800);
  int  o    = tid >> 1;          // output index [0,400)
  int  half = tid & 1;
  int  q    = (tid >> 1) & 3;    // gate
  int  j    = tid >> 3;          // unit [0,100)
  int  kbase = half ? 48 : 0;

  bool is_em = (tid >= 832 && tid < 832 + 2 * T);
  int  et = tid - 832;
  int  etag = et >> 1, ekh = et & 1;
  int  ekbase = ekh ? 48 : 0;

  // ---- load weights into registers (26 float2 = 52 VGPR) ----
  float2 w2[26];
  if (is_mv) {
    int row = q * 100 + j;                       // original gate-order row
    const float* wr = &Whh[(size_t)row * 100 + kbase];
#pragma unroll
    for (int i = 0; i < 13; i++) {
      float4 t4 = *(const float4*)&wr[4 * i];
      w2[2 * i]     = make_float2(t4.x, t4.y);
      w2[2 * i + 1] = make_float2(t4.z, t4.w);
    }
    if (half == 0) {                              // zero the overlap chunk
      w2[24] = make_float2(0.f, 0.f);
      w2[25] = make_float2(0.f, 0.f);
    }
  } else if (is_em) {
    const float* wr = &Wlin[etag * (2 * H) + dir * H + ekbase];
#pragma unroll
    for (int i = 0; i < 13; i++) {
      float4 t4 = *(const float4*)&wr[4 * i];
      w2[2 * i]     = make_float2(t4.x, t4.y);
      w2[2 * i + 1] = make_float2(t4.z, t4.w);
    }
    if (ekh == 0) {
      w2[24] = make_float2(0.f, 0.f);
      w2[25] = make_float2(0.f, 0.f);
    }
  }

  for (int i = tid; i < 224; i += 896) ((float*)h_lds)[i] = 0.f;
  for (int i = tid; i < S; i += 896) x_lds[i] = x[(size_t)b * S + i];
  if (tid < 400) {
    int tt0 = dir ? (S - 1) : 0;
    pre_lds[0][tid] = P[(size_t)x[(size_t)b * S + tt0] * 400 + tid];
  }
  float c = 0.f;
  __syncthreads();

  int buf = 0, pb = 0, prev_tt = 0;
  for (int t = 0; t < S; t++) {
    int tt = dir ? (S - 1 - t) : t;

    if (is_mv) {
      float prv = pre_lds[pb][o];                 // 2-lane broadcast (free)

      // gather pre-activation for step t+1 into the other pre buffer
      if (tid < 400 && t + 1 < S) {
        int ttn = dir ? (S - 2 - t) : (t + 1);
        int xv = x_lds[ttn];
        pre_lds[pb ^ 1][tid] = P[(size_t)xv * 400 + tid];
      }

      const float* hb = h_lds[buf] + kbase;
      float2 acc = make_float2(0.f, 0.f);
#pragma unroll
      for (int i = 0; i < 13; i++) {
        float4 h4 = *(const float4*)&hb[4 * i];
        acc.x += w2[2 * i].x * h4.x;     acc.y += w2[2 * i].y * h4.y;
        acc.x += w2[2 * i + 1].x * h4.z; acc.y += w2[2 * i + 1].y * h4.w;
      }
      float gpart = acc.x + acc.y;
      float g = gpart + __shfl_xor(gpart, 1) + prv;

      // own-gate activation: sigma for q!=2, tanh (=2*sigma(2g)-1) for q==2
      bool isg = (q == 2);
      float arg = isg ? (-2.f * g) : (-g);
      float e  = __expf(arg);
      float r  = fast_rcp(1.f + e);
      float act = isg ? (2.f * r - 1.f) : r;

      float v2 = __shfl_xor(act, 2);   // gate q^1
      float v4 = __shfl_xor(act, 4);   // gate q^2
      float v6 = __shfl_xor(act, 6);   // gate q^3
      bool q0 = (q & 1), q1 = (q & 2);
      float gi = q1 ? (q0 ? v6 : v4) : (q0 ? v2 : act);
      float gf = q1 ? (q0 ? v4 : v6) : (q0 ? act : v2);
      float gg = q1 ? (q0 ? v2 : act) : (q0 ? v6 : v4);
      float go = q1 ? (q0 ? act : v2) : (q0 ? v4 : v6);

      c = gf * c + gi * gg;
      float e2c = __expf(-2.f * c);
      float rc  = fast_rcp(1.f + e2c);
      float th  = 2.f * rc - 1.f;
      if ((tid & 7) == 0) h_lds[buf ^ 1][j] = go * th;
    } else if (is_em && t > 0) {
      const float* hb = h_lds[buf] + ekbase;
      float2 acc = make_float2(0.f, 0.f);
#pragma unroll
      for (int i = 0; i < 13; i++) {
        float4 h4 = *(const float4*)&hb[4 * i];
        acc.x += w2[2 * i].x * h4.x;     acc.y += w2[2 * i].y * h4.y;
        acc.x += w2[2 * i + 1].x * h4.z; acc.y += w2[2 * i + 1].y * h4.w;
      }
      float p = acc.x + acc.y;
      float full = p + __shfl_xor(p, 1);
      if (ekh == 0) em_lds[prev_tt * T + etag] = full;
    }
    __syncthreads();

    buf ^= 1; pb ^= 1; prev_tt = tt;
  }

  // final step's em projection (h(S-1) is in h_lds[buf])
  if (is_em) {
    const float* hb = h_lds[buf] + ekbase;
    float2 acc = make_float2(0.f, 0.f);
#pragma unroll
    for (int i = 0; i < 13; i++) {
      float4 h4 = *(const float4*)&hb[4 * i];
      acc.x += w2[2 * i].x * h4.x;     acc.y += w2[2 * i].y * h4.y;
      acc.x += w2[2 * i + 1].x * h4.z; acc.y += w2[2 * i + 1].y * h4.w;
    }
    float p = acc.x + acc.y;
    float full = p + __shfl_xor(p, 1);
    if (ekh == 0) em_lds[prev_tt * T + etag] = full;
  }
  __syncthreads();

  float* dst = em + (size_t)b * S * T;
  for (int i = tid; i < S * T; i += 896) dst[i] = em_lds[i];
}

// ---------------------------------------------------------------------------
// Kernel 3: Viterbi decode. One wave per batch row; lane = cur tag.
// Strict '>' preserves jnp.argmax first-max tie-break.
// out[0..B*S) = paths (as float), out[B*S..B*S+B) = best_score.
// ---------------------------------------------------------------------------
__global__ __launch_bounds__(64) void viterbi_kernel(
    const float* __restrict__ em_f, const float* __restrict__ em_b,
    const float* __restrict__ blin, const float* __restrict__ start,
    const float* __restrict__ trans, const float* __restrict__ endv,
    float* __restrict__ out)
{
  __shared__ unsigned char bp[S * T];
  int b = blockIdx.x;
  int lane = threadIdx.x;
  bool act = (lane < T);
  int tag = act ? lane : 0;

  float tc[T] = {};
  float bl = 0.f, en = 0.f;
  float score = -1e30f;
  if (act) {
    for (int p = 0; p < T; p++) tc[p] = trans[p * T + tag];
    bl = blin[tag];
    en = endv[tag];
    score = start[tag] + em_f[((size_t)b * S) * T + tag]
                       + em_b[((size_t)b * S) * T + tag] + bl;
  }

  for (int t = 1; t < S; t++) {
    float emv = 0.f;
    if (act) {
      emv = em_f[((size_t)b * S + t) * T + tag]
          + em_b[((size_t)b * S + t) * T + tag] + bl;
    }
    float best = -1e30f; int bestp = 0;
#pragma unroll
    for (int p = 0; p < T; p++) {
      float sp = __shfl(score, p);
      float cand = sp + tc[p];
      if (cand > best) { best = cand; bestp = p; }
    }
    if (act) {
      score = best + emv;
      bp[t * T + tag] = (unsigned char)bestp;
    }
  }
  if (act) score += en;
  __syncthreads();

  float bs = -1e30f; int last = 0;
#pragma unroll
  for (int p = 0; p < T; p++) {
    float sp = __shfl(score, p);
    if (sp > bs) { bs = sp; last = p; }
  }

  if (lane == 0) {
    out[(size_t)B * S + b] = bs;
    int cur = last;
    out[(size_t)b * S + (S - 1)] = (float)cur;
    for (int t = S - 1; t >= 1; t--) {
      cur = bp[t * T + cur];
      out[(size_t)b * S + (t - 1)] = (float)cur;
    }
  }
}

// ---------------------------------------------------------------------------
extern "C" void kernel_launch(void* const* d_in, const int* in_sizes, int n_in,
                              void* d_out, int out_size, void* d_ws, size_t ws_size,
                              hipStream_t stream)
{
  const int*   x     = (const int*)d_in[0];
  const float* embed = (const float*)d_in[2];
  const float* Wih_f = (const float*)d_in[3];
  const float* Whh_f = (const float*)d_in[4];
  const float* b_f   = (const float*)d_in[5];
  const float* Wih_b = (const float*)d_in[6];
  const float* Whh_b = (const float*)d_in[7];
  const float* b_b   = (const float*)d_in[8];
  const float* Wlin  = (const float*)d_in[9];
  const float* blin  = (const float*)d_in[10];
  const float* start = (const float*)d_in[11];
  const float* trans = (const float*)d_in[12];
  const float* endv  = (const float*)d_in[13];
  float* out = (float*)d_out;

  char* ws = (char*)d_ws;
  float* Pf   = (float*)ws;  ws += (size_t)V * 400 * sizeof(float);
  float* Pb   = (float*)ws;  ws += (size_t)V * 400 * sizeof(float);
  float* emf  = (float*)ws;  ws += (size_t)B * S * T * sizeof(float);
  float* emb_ = (float*)ws;  ws += (size_t)B * S * T * sizeof(float);

  precompute_P<<<dim3(13, 469), 256, 0, stream>>>(embed, Wih_f, b_f, Wih_b, b_b, Pf, Pb);
  lstm_kernel<<<dim3(512), 896, 0, stream>>>(x, Pf, Pb, Whh_f, Whh_b, Wlin, emf, emb_);
  viterbi_kernel<<<dim3(256), 64, 0, stream>>>(emf, emb_, blin, start, trans, endv, out);
}

// Round 4
// 1195.304 us; speedup vs baseline: 1.1727x; 1.1727x over previous
//
#include <hip/hip_runtime.h>

#define V 30000
#define E 100
#define H 100
#define T 9
#define B 256
#define S 512

__device__ __forceinline__ float fast_rcp(float x) { return __builtin_amdgcn_rcpf(x); }
__device__ __forceinline__ float2 pkfma(float2 a, float2 b, float2 c) {
  return make_float2(fmaf(a.x, b.x, c.x), fmaf(a.y, b.y, c.y));
}

// ---------------------------------------------------------------------------
// Kernel 1: P_d = embed @ Wih_d^T + b_d, PERMUTED columns:
//   P'[v][4*j + q] = P[v][q*100 + j]  (q = gate, j = unit)
// ---------------------------------------------------------------------------
#define LDE 68

__global__ __launch_bounds__(256) void precompute_P(
    const float* __restrict__ embed,
    const float* __restrict__ Wih_f, const float* __restrict__ b_f,
    const float* __restrict__ Wih_b, const float* __restrict__ b_b,
    float* __restrict__ Pf, float* __restrict__ Pb)
{
  __shared__ __align__(16) float eT[100 * LDE];
  __shared__ __align__(16) float wT[100 * LDE];
  int tid = threadIdx.x;
  int o0 = blockIdx.x * 64;
  int v0 = blockIdx.y * 64;

  for (int idx = tid; idx < 64 * 100; idx += 256) {
    int k = idx % 100, vi = idx / 100;
    int v = v0 + vi;
    eT[k * LDE + vi] = (v < V) ? embed[v * E + k] : 0.0f;
  }
  for (int idx = tid; idx < 64 * 100; idx += 256) {
    int k = idx % 100, oi = idx / 100;
    int o = o0 + oi;
    float val = 0.0f;
    if (o < 400) val = Wih_f[o * E + k];
    else if (o < 800) val = Wih_b[(o - 400) * E + k];
    wT[k * LDE + oi] = val;
  }
  __syncthreads();

  int tx = tid & 15, ty = tid >> 4;
  int vi0 = ty * 4, oi0 = tx * 4;
  float acc[4][4];
#pragma unroll
  for (int i = 0; i < 4; i++)
#pragma unroll
    for (int j = 0; j < 4; j++) acc[i][j] = 0.f;

  for (int k = 0; k < 100; k++) {
    float4 ev = *(const float4*)&eT[k * LDE + vi0];
    float4 wv = *(const float4*)&wT[k * LDE + oi0];
    float e[4] = {ev.x, ev.y, ev.z, ev.w};
    float w[4] = {wv.x, wv.y, wv.z, wv.w};
#pragma unroll
    for (int i = 0; i < 4; i++)
#pragma unroll
      for (int j = 0; j < 4; j++) acc[i][j] += e[i] * w[j];
  }

  for (int i = 0; i < 4; i++) {
    int v = v0 + vi0 + i;
    if (v >= V) break;
    for (int j = 0; j < 4; j++) {
      int o = o0 + oi0 + j;
      if (o >= 800) continue;
      int oo = (o < 400) ? o : (o - 400);
      int perm = 4 * (oo % 100) + (oo / 100);
      float bias = (o < 400) ? b_f[oo] : b_b[oo];
      float* dst = (o < 400) ? Pf : Pb;
      dst[(size_t)v * 400 + perm] = acc[i][j] + bias;
    }
  }
}

// ---------------------------------------------------------------------------
// Kernel 2: LSTM recurrence. One (dir,row) chain per block; 512 blocks,
// block = 512 threads (8 waves), 2 blocks/CU.
//   tid<400: matvec. og=tid>>2 (unit), kq=tid&3 (K-quarter). Thread computes
//     4 gate-partials of unit og over k in [24kq,24kq+24) + element 96+kq.
//     One h float4 read feeds 8 pk_fma (4 gates x 2). Quad reduce-scatter
//     (shfl_xor 2 then 1) lands gate kq on lane kq; own-gate activation;
//     quad butterfly (xor 1,2,3) rebuilds all gates; redundant c/h update;
//     lane kq==0 writes h. Also gathers next pre row (coalesced, dbuf).
//   tid in [448,484): em projection, (tag=et>>2, kq=et&3), same K-split,
//     quad all-reduce, lane kq==0 writes em_lds.
// ONE barrier per step; K-loop unrolled x2 for compile-time buffers.
// ---------------------------------------------------------------------------
__global__ __launch_bounds__(512, 4) void lstm_kernel(
    const int* __restrict__ x,
    const float* __restrict__ Pf, const float* __restrict__ Pb,
    const float* __restrict__ Whh_f, const float* __restrict__ Whh_b,
    const float* __restrict__ Wlin,
    float* __restrict__ em_f, float* __restrict__ em_b)
{
  __shared__ __align__(16) float h_lds[2][104];
  __shared__ __align__(16) float pre_lds[2][400];
  __shared__ int   x_lds[S];
  __shared__ float em_lds[S * T];

  int tid = threadIdx.x;
  int dir = blockIdx.x & 1;
  int b   = blockIdx.x >> 1;

  const float* P   = dir ? Pb : Pf;
  const float* Whh = dir ? Whh_b : Whh_f;
  float*       em  = dir ? em_b : em_f;

  bool is_mv = (tid < 400);
  int  og = tid >> 2, kq = tid & 3;
  bool b1 = (kq & 2) != 0, b0 = (kq & 1) != 0;

  bool is_em = (tid >= 448 && tid < 448 + 4 * T);
  int  et = tid - 448;
  int  etag = et >> 2, ekq = et & 3;

  // weights: 4 outputs x (24 quarter + 1 remainder) = 100 VGPRs
  float2 w2[4][12];
  float  wr[4];
  if (is_mv) {
#pragma unroll
    for (int q = 0; q < 4; q++) {
      const float* row = &Whh[(size_t)(q * 100 + og) * 100];
#pragma unroll
      for (int i = 0; i < 6; i++) {
        float4 t4 = *(const float4*)&row[24 * kq + 4 * i];
        w2[q][2 * i]     = make_float2(t4.x, t4.y);
        w2[q][2 * i + 1] = make_float2(t4.z, t4.w);
      }
      wr[q] = row[96 + kq];
    }
  } else if (is_em) {
    const float* row = &Wlin[etag * (2 * H) + dir * H];
#pragma unroll
    for (int i = 0; i < 6; i++) {
      float4 t4 = *(const float4*)&row[24 * ekq + 4 * i];
      w2[0][2 * i]     = make_float2(t4.x, t4.y);
      w2[0][2 * i + 1] = make_float2(t4.z, t4.w);
    }
    wr[0] = row[96 + ekq];
  }

  for (int i = tid; i < 208; i += 512) ((float*)h_lds)[i] = 0.f;
  for (int i = tid; i < S; i += 512) x_lds[i] = x[(size_t)b * S + i];
  if (tid < 400) {
    int tt0 = dir ? (S - 1) : 0;
    pre_lds[0][tid] = P[(size_t)x[(size_t)b * S + tt0] * 400 + tid];
  }
  float c = 0.f;
  int prev_tt = 0;
  __syncthreads();

  auto step = [&](int bufc, int t) {
    int tt = dir ? (S - 1 - t) : t;
    if (is_mv) {
      float prv = pre_lds[bufc][tid];
      if (t + 1 < S) {
        int ttn = dir ? (S - 2 - t) : (t + 1);
        int xv = x_lds[ttn];
        pre_lds[bufc ^ 1][tid] = P[(size_t)xv * 400 + tid];
      }
      const float* hq = &h_lds[bufc][24 * kq];
      float2 a0 = {0, 0}, a1 = {0, 0}, a2 = {0, 0}, a3 = {0, 0};
#pragma unroll
      for (int i = 0; i < 6; i++) {
        float4 h4 = *(const float4*)&hq[4 * i];
        float2 hlo = make_float2(h4.x, h4.y), hhi = make_float2(h4.z, h4.w);
        a0 = pkfma(w2[0][2 * i], hlo, a0); a0 = pkfma(w2[0][2 * i + 1], hhi, a0);
        a1 = pkfma(w2[1][2 * i], hlo, a1); a1 = pkfma(w2[1][2 * i + 1], hhi, a1);
        a2 = pkfma(w2[2][2 * i], hlo, a2); a2 = pkfma(w2[2][2 * i + 1], hhi, a2);
        a3 = pkfma(w2[3][2 * i], hlo, a3); a3 = pkfma(w2[3][2 * i + 1], hhi, a3);
      }
      float hr = h_lds[bufc][96 + kq];
      float p0 = fmaf(wr[0], hr, a0.x + a0.y);
      float p1 = fmaf(wr[1], hr, a1.x + a1.y);
      float p2 = fmaf(wr[2], hr, a2.x + a2.y);
      float p3 = fmaf(wr[3], hr, a3.x + a3.y);

      // quad reduce-scatter: gate kq lands on lane kq
      float s0a = b1 ? p0 : p2;
      float s1a = b1 ? p1 : p3;
      float r0 = __shfl_xor(s0a, 2);
      float r1 = __shfl_xor(s1a, 2);
      float s0 = (b1 ? p2 : p0) + r0;   // gate 2*b1
      float s1 = (b1 ? p3 : p1) + r1;   // gate 2*b1+1
      float snd  = b0 ? s0 : s1;
      float kept = b0 ? s1 : s0;
      float g = kept + __shfl_xor(snd, 1) + prv;

      // own-gate activation (tanh for gate 2, sigmoid else)
      bool isg = (kq == 2);
      float arg = isg ? (-2.f * g) : (-g);
      float e = __expf(arg);
      float r = fast_rcp(1.f + e);
      float act = isg ? (2.f * r - 1.f) : r;

      // quad butterfly: value for gate q is at xor-distance kq^q
      float v1 = __shfl_xor(act, 1);
      float v2 = __shfl_xor(act, 2);
      float v3 = __shfl_xor(act, 3);
      float gi = b1 ? (b0 ? v3 : v2) : (b0 ? v1 : act);
      float gf = b1 ? (b0 ? v2 : v3) : (b0 ? act : v1);
      float gg = b1 ? (b0 ? v1 : act) : (b0 ? v3 : v2);
      float go = b1 ? (b0 ? act : v1) : (b0 ? v2 : v3);

      c = fmaf(gf, c, gi * gg);
      float e2c = __expf(-2.f * c);
      float th  = 2.f * fast_rcp(1.f + e2c) - 1.f;
      if (kq == 0) h_lds[bufc ^ 1][og] = go * th;
    } else if (is_em && t > 0) {
      const float* hq = &h_lds[bufc][24 * ekq];
      float2 a = {0, 0};
#pragma unroll
      for (int i = 0; i < 6; i++) {
        float4 h4 = *(const float4*)&hq[4 * i];
        a = pkfma(w2[0][2 * i], make_float2(h4.x, h4.y), a);
        a = pkfma(w2[0][2 * i + 1], make_float2(h4.z, h4.w), a);
      }
      float hr = h_lds[bufc][96 + ekq];
      float p = fmaf(wr[0], hr, a.x + a.y);
      p += __shfl_xor(p, 1);
      p += __shfl_xor(p, 2);
      if (ekq == 0) em_lds[prev_tt * T + etag] = p;
    }
    __syncthreads();
    prev_tt = tt;
  };

  for (int t = 0; t < S; t += 2) {
    step(0, t);
    step(1, t + 1);
  }

  // final em projection from h(S-1) (now in h_lds[0])
  if (is_em) {
    const float* hq = &h_lds[0][24 * ekq];
    float2 a = {0, 0};
#pragma unroll
    for (int i = 0; i < 6; i++) {
      float4 h4 = *(const float4*)&hq[4 * i];
      a = pkfma(w2[0][2 * i], make_float2(h4.x, h4.y), a);
      a = pkfma(w2[0][2 * i + 1], make_float2(h4.z, h4.w), a);
    }
    float hr = h_lds[0][96 + ekq];
    float p = fmaf(wr[0], hr, a.x + a.y);
    p += __shfl_xor(p, 1);
    p += __shfl_xor(p, 2);
    if (ekq == 0) em_lds[prev_tt * T + etag] = p;
  }
  __syncthreads();

  float* dst = em + (size_t)b * S * T;
  for (int i = tid; i < S * T; i += 512) dst[i] = em_lds[i];
}

// ---------------------------------------------------------------------------
// Kernel 3: Viterbi decode, software-pipelined em loads.
// One wave per batch row; lane = cur tag; strict '>' = jnp.argmax tie-break.
// ---------------------------------------------------------------------------
__global__ __launch_bounds__(64) void viterbi_kernel(
    const float* __restrict__ em_f, const float* __restrict__ em_b,
    const float* __restrict__ blin, const float* __restrict__ start,
    const float* __restrict__ trans, const float* __restrict__ endv,
    float* __restrict__ out)
{
  __shared__ unsigned char bp[S * T];
  int b = blockIdx.x;
  int lane = threadIdx.x;
  bool act = (lane < T);
  int tag = act ? lane : 0;

  float tc[T] = {};
  float bl = 0.f, en = 0.f;
  float score = -1e30f;
  if (act) {
    for (int p = 0; p < T; p++) tc[p] = trans[p * T + tag];
    bl = blin[tag];
    en = endv[tag];
    score = start[tag] + em_f[((size_t)b * S) * T + tag]
                       + em_b[((size_t)b * S) * T + tag] + bl;
  }

  float cf = 0.f, cb = 0.f;
  if (act) {
    cf = em_f[((size_t)b * S + 1) * T + tag];
    cb = em_b[((size_t)b * S + 1) * T + tag];
  }

  for (int t = 1; t < S; t++) {
    float nf = 0.f, nb = 0.f;
    if (act && t + 1 < S) {
      nf = em_f[((size_t)b * S + t + 1) * T + tag];
      nb = em_b[((size_t)b * S + t + 1) * T + tag];
    }
    float best = -1e30f; int bestp = 0;
#pragma unroll
    for (int p = 0; p < T; p++) {
      float sp = __shfl(score, p);
      float cand = sp + tc[p];
      if (cand > best) { best = cand; bestp = p; }
    }
    if (act) {
      score = best + cf + cb + bl;
      bp[t * T + tag] = (unsigned char)bestp;
    }
    cf = nf; cb = nb;
  }
  if (act) score += en;
  __syncthreads();

  float bs = -1e30f; int last = 0;
#pragma unroll
  for (int p = 0; p < T; p++) {
    float sp = __shfl(score, p);
    if (sp > bs) { bs = sp; last = p; }
  }

  if (lane == 0) {
    out[(size_t)B * S + b] = bs;
    int cur = last;
    out[(size_t)b * S + (S - 1)] = (float)cur;
    for (int t = S - 1; t >= 1; t--) {
      cur = bp[t * T + cur];
      out[(size_t)b * S + (t - 1)] = (float)cur;
    }
  }
}

// ---------------------------------------------------------------------------
extern "C" void kernel_launch(void* const* d_in, const int* in_sizes, int n_in,
                              void* d_out, int out_size, void* d_ws, size_t ws_size,
                              hipStream_t stream)
{
  const int*   x     = (const int*)d_in[0];
  const float* embed = (const float*)d_in[2];
  const float* Wih_f = (const float*)d_in[3];
  const float* Whh_f = (const float*)d_in[4];
  const float* b_f   = (const float*)d_in[5];
  const float* Wih_b = (const float*)d_in[6];
  const float* Whh_b = (const float*)d_in[7];
  const float* b_b   = (const float*)d_in[8];
  const float* Wlin  = (const float*)d_in[9];
  const float* blin  = (const float*)d_in[10];
  const float* start = (const float*)d_in[11];
  const float* trans = (const float*)d_in[12];
  const float* endv  = (const float*)d_in[13];
  float* out = (float*)d_out;

  char* ws = (char*)d_ws;
  float* Pf   = (float*)ws;  ws += (size_t)V * 400 * sizeof(float);
  float* Pb   = (float*)ws;  ws += (size_t)V * 400 * sizeof(float);
  float* emf  = (float*)ws;  ws += (size_t)B * S * T * sizeof(float);
  float* emb_ = (float*)ws;  ws += (size_t)B * S * T * sizeof(float);

  precompute_P<<<dim3(13, 469), 256, 0, stream>>>(embed, Wih_f, b_f, Wih_b, b_b, Pf, Pb);
  lstm_kernel<<<dim3(512), 512, 0, stream>>>(x, Pf, Pb, Whh_f, Whh_b, Wlin, emf, emb_);
  viterbi_kernel<<<dim3(256), 64, 0, stream>>>(emf, emb_, blin, start, trans, endv, out);
}

// Round 5
// 1129.771 us; speedup vs baseline: 1.2408x; 1.0580x over previous
//
#include <hip/hip_runtime.h>

#define V 30000
#define E 100
#define H 100
#define T 9
#define B 256
#define S 512

__device__ __forceinline__ float fast_rcp(float x) { return __builtin_amdgcn_rcpf(x); }
__device__ __forceinline__ float2 pkfma(float2 a, float2 b, float2 c) {
  return make_float2(fmaf(a.x, b.x, c.x), fmaf(a.y, b.y, c.y));
}

// quad all-reduce via DPP quad_perm (VALU pipe, no DS): xor1 then xor2
__device__ __forceinline__ float quad_allreduce(float x) {
  int t = __builtin_amdgcn_update_dpp(0, __builtin_bit_cast(int, x), 0xB1, 0xF, 0xF, true); // [1,0,3,2]
  x += __builtin_bit_cast(float, t);
  t = __builtin_amdgcn_update_dpp(0, __builtin_bit_cast(int, x), 0x4E, 0xF, 0xF, true);     // [2,3,0,1]
  x += __builtin_bit_cast(float, t);
  return x;
}

// ---------------------------------------------------------------------------
// Kernel 1: P_d = embed @ Wih_d^T + b_d, PERMUTED columns:
//   P'[v][4*j + q] = P[v][q*100 + j]  (q = gate, j = unit)
// ---------------------------------------------------------------------------
#define LDE 68

__global__ __launch_bounds__(256) void precompute_P(
    const float* __restrict__ embed,
    const float* __restrict__ Wih_f, const float* __restrict__ b_f,
    const float* __restrict__ Wih_b, const float* __restrict__ b_b,
    float* __restrict__ Pf, float* __restrict__ Pb)
{
  __shared__ __align__(16) float eT[100 * LDE];
  __shared__ __align__(16) float wT[100 * LDE];
  int tid = threadIdx.x;
  int o0 = blockIdx.x * 64;
  int v0 = blockIdx.y * 64;

  for (int idx = tid; idx < 64 * 100; idx += 256) {
    int k = idx % 100, vi = idx / 100;
    int v = v0 + vi;
    eT[k * LDE + vi] = (v < V) ? embed[v * E + k] : 0.0f;
  }
  for (int idx = tid; idx < 64 * 100; idx += 256) {
    int k = idx % 100, oi = idx / 100;
    int o = o0 + oi;
    float val = 0.0f;
    if (o < 400) val = Wih_f[o * E + k];
    else if (o < 800) val = Wih_b[(o - 400) * E + k];
    wT[k * LDE + oi] = val;
  }
  __syncthreads();

  int tx = tid & 15, ty = tid >> 4;
  int vi0 = ty * 4, oi0 = tx * 4;
  float acc[4][4];
#pragma unroll
  for (int i = 0; i < 4; i++)
#pragma unroll
    for (int j = 0; j < 4; j++) acc[i][j] = 0.f;

  for (int k = 0; k < 100; k++) {
    float4 ev = *(const float4*)&eT[k * LDE + vi0];
    float4 wv = *(const float4*)&wT[k * LDE + oi0];
    float e[4] = {ev.x, ev.y, ev.z, ev.w};
    float w[4] = {wv.x, wv.y, wv.z, wv.w};
#pragma unroll
    for (int i = 0; i < 4; i++)
#pragma unroll
      for (int j = 0; j < 4; j++) acc[i][j] += e[i] * w[j];
  }

  for (int i = 0; i < 4; i++) {
    int v = v0 + vi0 + i;
    if (v >= V) break;
    for (int j = 0; j < 4; j++) {
      int o = o0 + oi0 + j;
      if (o >= 800) continue;
      int oo = (o < 400) ? o : (o - 400);
      int perm = 4 * (oo % 100) + (oo / 100);
      float bias = (o < 400) ? b_f[oo] : b_b[oo];
      float* dst = (o < 400) ? Pf : Pb;
      dst[(size_t)v * 400 + perm] = acc[i][j] + bias;
    }
  }
}

// ---------------------------------------------------------------------------
// Kernel 2: LSTM recurrence. One (dir,row) chain per block; 512 blocks,
// block = 512 threads (8 waves), 2 blocks/CU (16 waves/CU = 4/EU).
// amdgpu_waves_per_eu(4,4) pins the VGPR budget at 128 so the 100-float
// weight set stays in REAL VGPRs (R4's allocator targeted 8 waves/EU ->
// 64 VGPRs -> weights in AGPRs -> v_accvgpr_read per FMA).
//   tid<400: og=tid>>2 (unit), kq=tid&3 (K-quarter of 24 + 1 remainder).
//     4 gate partials per thread; prv injected via accumulator init on the
//     own-gate slot; DPP quad all-reduce gives ALL 4 gate pre-acts to every
//     lane (no scatter/butterfly); redundant activations + c/h update;
//     lane kq==0 writes h. pre prefetched in a REGISTER (no LDS round trip;
//     global->VGPR loads are not drained by __syncthreads).
//   tid in [448,484): em projection, DPP quad all-reduce.
// ONE barrier per step.
// ---------------------------------------------------------------------------
__global__ __attribute__((amdgpu_flat_work_group_size(512, 512), amdgpu_waves_per_eu(4, 4)))
void lstm_kernel(
    const int* __restrict__ x,
    const float* __restrict__ Pf, const float* __restrict__ Pb,
    const float* __restrict__ Whh_f, const float* __restrict__ Whh_b,
    const float* __restrict__ Wlin,
    float* __restrict__ em_f, float* __restrict__ em_b)
{
  __shared__ __align__(16) float h_lds[2][104];
  __shared__ int   x_lds[S];
  __shared__ float em_lds[S * T];

  int tid = threadIdx.x;
  int dir = blockIdx.x & 1;
  int b   = blockIdx.x >> 1;

  const float* P   = dir ? Pb : Pf;
  const float* Whh = dir ? Whh_b : Whh_f;
  float*       em  = dir ? em_b : em_f;

  bool is_mv = (tid < 400);
  int  og = tid >> 2, kq = tid & 3;

  bool is_em = (tid >= 448 && tid < 448 + 4 * T);
  int  et = tid - 448;
  int  etag = et >> 2, ekq = et & 3;

  // weights: 4 outputs x (24 quarter + 1 remainder) = 100 VGPRs
  float2 w2[4][12];
  float  wr[4];
  if (is_mv) {
#pragma unroll
    for (int q = 0; q < 4; q++) {
      const float* row = &Whh[(size_t)(q * 100 + og) * 100];
#pragma unroll
      for (int i = 0; i < 6; i++) {
        float4 t4 = *(const float4*)&row[24 * kq + 4 * i];
        w2[q][2 * i]     = make_float2(t4.x, t4.y);
        w2[q][2 * i + 1] = make_float2(t4.z, t4.w);
      }
      wr[q] = row[96 + kq];
    }
  } else if (is_em) {
    const float* row = &Wlin[etag * (2 * H) + dir * H];
#pragma unroll
    for (int i = 0; i < 6; i++) {
      float4 t4 = *(const float4*)&row[24 * ekq + 4 * i];
      w2[0][2 * i]     = make_float2(t4.x, t4.y);
      w2[0][2 * i + 1] = make_float2(t4.z, t4.w);
    }
    wr[0] = row[96 + ekq];
  }

  for (int i = tid; i < 208; i += 512) ((float*)h_lds)[i] = 0.f;
  for (int i = tid; i < S; i += 512) x_lds[i] = x[(size_t)b * S + i];
  float c = 0.f;
  float pre = 0.f;
  if (is_mv) {
    int tt0 = dir ? (S - 1) : 0;
    pre = P[(size_t)x[(size_t)b * S + tt0] * 400 + tid];
  }
  int prev_tt = 0;
  __syncthreads();

  auto step = [&](int bufc, int t) {
    int tt = dir ? (S - 1 - t) : t;
    if (is_mv) {
      float prv = pre;
      if (t + 1 < S) {                        // register prefetch for t+1
        int ttn = dir ? (S - 2 - t) : (t + 1);
        int xv = x_lds[ttn];
        pre = P[(size_t)xv * 400 + tid];
      }
      const float* hq = &h_lds[bufc][24 * kq];
      // prv belongs to gate kq of unit og -> inject via accumulator init
      float2 a0 = make_float2((kq == 0) ? prv : 0.f, 0.f);
      float2 a1 = make_float2((kq == 1) ? prv : 0.f, 0.f);
      float2 a2 = make_float2((kq == 2) ? prv : 0.f, 0.f);
      float2 a3 = make_float2((kq == 3) ? prv : 0.f, 0.f);
#pragma unroll
      for (int i = 0; i < 6; i++) {
        float4 h4 = *(const float4*)&hq[4 * i];
        float2 hlo = make_float2(h4.x, h4.y), hhi = make_float2(h4.z, h4.w);
        a0 = pkfma(w2[0][2 * i], hlo, a0); a0 = pkfma(w2[0][2 * i + 1], hhi, a0);
        a1 = pkfma(w2[1][2 * i], hlo, a1); a1 = pkfma(w2[1][2 * i + 1], hhi, a1);
        a2 = pkfma(w2[2][2 * i], hlo, a2); a2 = pkfma(w2[2][2 * i + 1], hhi, a2);
        a3 = pkfma(w2[3][2 * i], hlo, a3); a3 = pkfma(w2[3][2 * i + 1], hhi, a3);
      }
      float hr = h_lds[bufc][96 + kq];
      float s0 = quad_allreduce(fmaf(wr[0], hr, a0.x + a0.y));  // gate i
      float s1 = quad_allreduce(fmaf(wr[1], hr, a1.x + a1.y));  // gate f
      float s2 = quad_allreduce(fmaf(wr[2], hr, a2.x + a2.y));  // gate g
      float s3 = quad_allreduce(fmaf(wr[3], hr, a3.x + a3.y));  // gate o

      float gi = fast_rcp(1.f + __expf(-s0));
      float gf = fast_rcp(1.f + __expf(-s1));
      float tg = 2.f * fast_rcp(1.f + __expf(-2.f * s2)) - 1.f;
      float go = fast_rcp(1.f + __expf(-s3));

      c = fmaf(gf, c, gi * tg);
      float th = 2.f * fast_rcp(1.f + __expf(-2.f * c)) - 1.f;
      if (kq == 0) h_lds[bufc ^ 1][og] = go * th;
    } else if (is_em && t > 0) {
      const float* hq = &h_lds[bufc][24 * ekq];
      float2 a = {0, 0};
#pragma unroll
      for (int i = 0; i < 6; i++) {
        float4 h4 = *(const float4*)&hq[4 * i];
        a = pkfma(w2[0][2 * i], make_float2(h4.x, h4.y), a);
        a = pkfma(w2[0][2 * i + 1], make_float2(h4.z, h4.w), a);
      }
      float hr = h_lds[bufc][96 + ekq];
      float p = quad_allreduce(fmaf(wr[0], hr, a.x + a.y));
      if (ekq == 0) em_lds[prev_tt * T + etag] = p;
    }
    __syncthreads();
    prev_tt = tt;
  };

  for (int t = 0; t < S; t += 2) {
    step(0, t);
    step(1, t + 1);
  }

  // final em projection from h(S-1) (now in h_lds[0])
  if (is_em) {
    const float* hq = &h_lds[0][24 * ekq];
    float2 a = {0, 0};
#pragma unroll
    for (int i = 0; i < 6; i++) {
      float4 h4 = *(const float4*)&hq[4 * i];
      a = pkfma(w2[0][2 * i], make_float2(h4.x, h4.y), a);
      a = pkfma(w2[0][2 * i + 1], make_float2(h4.z, h4.w), a);
    }
    float hr = h_lds[0][96 + ekq];
    float p = quad_allreduce(fmaf(wr[0], hr, a.x + a.y));
    if (ekq == 0) em_lds[prev_tt * T + etag] = p;
  }
  __syncthreads();

  float* dst = em + (size_t)b * S * T;
  for (int i = tid; i < S * T; i += 512) dst[i] = em_lds[i];
}

// ---------------------------------------------------------------------------
// Kernel 3: Viterbi decode, 4-deep em prefetch pipeline (8 loads in flight
// covers ~900-cycle HBM latency; 1-deep left it exposed every step).
// One wave per batch row; lane = cur tag; strict '>' = jnp.argmax tie-break.
// ---------------------------------------------------------------------------
__global__ __launch_bounds__(64) void viterbi_kernel(
    const float* __restrict__ em_f, const float* __restrict__ em_b,
    const float* __restrict__ blin, const float* __restrict__ start,
    const float* __restrict__ trans, const float* __restrict__ endv,
    float* __restrict__ out)
{
  __shared__ unsigned char bp[S * T];
  int b = blockIdx.x;
  int lane = threadIdx.x;
  bool act = (lane < T);
  int tag = act ? lane : 0;

  float tc[T] = {};
  float bl = 0.f, en = 0.f;
  float score = -1e30f;
  if (act) {
    for (int p = 0; p < T; p++) tc[p] = trans[p * T + tag];
    bl = blin[tag];
    en = endv[tag];
    score = start[tag] + em_f[((size_t)b * S) * T + tag]
                       + em_b[((size_t)b * S) * T + tag] + bl;
  }

  float cf[4] = {}, cb[4] = {};
  if (act) {
#pragma unroll
    for (int j = 0; j < 4; j++) {
      cf[j] = em_f[((size_t)b * S + 1 + j) * T + tag];
      cb[j] = em_b[((size_t)b * S + 1 + j) * T + tag];
    }
  }

  for (int t = 1; t < S; t++) {
    int slot = (t - 1) & 3;
    float evf = cf[slot], evb = cb[slot];
    if (act && t + 4 < S) {
      cf[slot] = em_f[((size_t)b * S + t + 4) * T + tag];
      cb[slot] = em_b[((size_t)b * S + t + 4) * T + tag];
    }
    float best = -1e30f; int bestp = 0;
#pragma unroll
    for (int p = 0; p < T; p++) {
      float sp = __shfl(score, p);
      float cand = sp + tc[p];
      if (cand > best) { best = cand; bestp = p; }
    }
    if (act) {
      score = best + evf + evb + bl;
      bp[t * T + tag] = (unsigned char)bestp;
    }
  }
  if (act) score += en;
  __syncthreads();

  float bs = -1e30f; int last = 0;
#pragma unroll
  for (int p = 0; p < T; p++) {
    float sp = __shfl(score, p);
    if (sp > bs) { bs = sp; last = p; }
  }

  if (lane == 0) {
    out[(size_t)B * S + b] = bs;
    int cur = last;
    out[(size_t)b * S + (S - 1)] = (float)cur;
    for (int t = S - 1; t >= 1; t--) {
      cur = bp[t * T + cur];
      out[(size_t)b * S + (t - 1)] = (float)cur;
    }
  }
}

// ---------------------------------------------------------------------------
extern "C" void kernel_launch(void* const* d_in, const int* in_sizes, int n_in,
                              void* d_out, int out_size, void* d_ws, size_t ws_size,
                              hipStream_t stream)
{
  const int*   x     = (const int*)d_in[0];
  const float* embed = (const float*)d_in[2];
  const float* Wih_f = (const float*)d_in[3];
  const float* Whh_f = (const float*)d_in[4];
  const float* b_f   = (const float*)d_in[5];
  const float* Wih_b = (const float*)d_in[6];
  const float* Whh_b = (const float*)d_in[7];
  const float* b_b   = (const float*)d_in[8];
  const float* Wlin  = (const float*)d_in[9];
  const float* blin  = (const float*)d_in[10];
  const float* start = (const float*)d_in[11];
  const float* trans = (const float*)d_in[12];
  const float* endv  = (const float*)d_in[13];
  float* out = (float*)d_out;

  char* ws = (char*)d_ws;
  float* Pf   = (float*)ws;  ws += (size_t)V * 400 * sizeof(float);
  float* Pb   = (float*)ws;  ws += (size_t)V * 400 * sizeof(float);
  float* emf  = (float*)ws;  ws += (size_t)B * S * T * sizeof(float);
  float* emb_ = (float*)ws;  ws += (size_t)B * S * T * sizeof(float);

  precompute_P<<<dim3(13, 469), 256, 0, stream>>>(embed, Wih_f, b_f, Wih_b, b_b, Pf, Pb);
  lstm_kernel<<<dim3(512), 512, 0, stream>>>(x, Pf, Pb, Whh_f, Whh_b, Wlin, emf, emb_);
  viterbi_kernel<<<dim3(256), 64, 0, stream>>>(emf, emb_, blin, start, trans, endv, out);
}

// Round 6
// 960.344 us; speedup vs baseline: 1.4597x; 1.1764x over previous
//
#include <hip/hip_runtime.h>

#define V 30000
#define E 100
#define H 100
#define T 9
#define B 256
#define S 512

typedef float v2f __attribute__((ext_vector_type(2)));

__device__ __forceinline__ float fast_rcp(float x) { return __builtin_amdgcn_rcpf(x); }

template <int PAT>
__device__ __forceinline__ float dpp_mov(float x) {
  int t = __builtin_amdgcn_update_dpp(0, __builtin_bit_cast(int, x), PAT, 0xF, 0xF, true);
  return __builtin_bit_cast(float, t);
}

// ---------------------------------------------------------------------------
// Kernel 1: P_d = embed @ Wih_d^T + b_d, PERMUTED columns:
//   P'[v][4*j + q] = P[v][q*100 + j]  (q = gate, j = unit)
// ---------------------------------------------------------------------------
#define LDE 72   // 72%32=8 -> 4-way write conflict (68 gave 8-way); 288B rows keep 16B align

__global__ __launch_bounds__(256) void precompute_P(
    const float* __restrict__ embed,
    const float* __restrict__ Wih_f, const float* __restrict__ b_f,
    const float* __restrict__ Wih_b, const float* __restrict__ b_b,
    float* __restrict__ Pf, float* __restrict__ Pb)
{
  __shared__ __align__(16) float eT[100 * LDE];
  __shared__ __align__(16) float wT[100 * LDE];
  int tid = threadIdx.x;
  int o0 = blockIdx.x * 64;
  int v0 = blockIdx.y * 64;

  for (int idx = tid; idx < 64 * 100; idx += 256) {
    int k = idx % 100, vi = idx / 100;
    int v = v0 + vi;
    eT[k * LDE + vi] = (v < V) ? embed[v * E + k] : 0.0f;
  }
  for (int idx = tid; idx < 64 * 100; idx += 256) {
    int k = idx % 100, oi = idx / 100;
    int o = o0 + oi;
    float val = 0.0f;
    if (o < 400) val = Wih_f[o * E + k];
    else if (o < 800) val = Wih_b[(o - 400) * E + k];
    wT[k * LDE + oi] = val;
  }
  __syncthreads();

  int tx = tid & 15, ty = tid >> 4;
  int vi0 = ty * 4, oi0 = tx * 4;
  float acc[4][4];
#pragma unroll
  for (int i = 0; i < 4; i++)
#pragma unroll
    for (int j = 0; j < 4; j++) acc[i][j] = 0.f;

  for (int k = 0; k < 100; k++) {
    float4 ev = *(const float4*)&eT[k * LDE + vi0];
    float4 wv = *(const float4*)&wT[k * LDE + oi0];
    float e[4] = {ev.x, ev.y, ev.z, ev.w};
    float w[4] = {wv.x, wv.y, wv.z, wv.w};
#pragma unroll
    for (int i = 0; i < 4; i++)
#pragma unroll
      for (int j = 0; j < 4; j++) acc[i][j] += e[i] * w[j];
  }

  for (int i = 0; i < 4; i++) {
    int v = v0 + vi0 + i;
    if (v >= V) break;
    for (int j = 0; j < 4; j++) {
      int o = o0 + oi0 + j;
      if (o >= 800) continue;
      int oo = (o < 400) ? o : (o - 400);
      int perm = 4 * (oo % 100) + (oo / 100);
      float bias = (o < 400) ? b_f[oo] : b_b[oo];
      float* dst = (o < 400) ? Pf : Pb;
      dst[(size_t)v * 400 + perm] = acc[i][j] + bias;
    }
  }
}

// ---------------------------------------------------------------------------
// Kernel 2: LSTM recurrence. One (dir,row) chain per block; 512 blocks,
// block = 512 threads (8 waves), 2 blocks/CU.
//   tid<400: og=tid>>2 (unit), kq=tid&3 (K-quarter: 24 + 1 remainder elem).
//     Packed v_pk_fma accumulation (ext_vector + elementwise_fma), DPP
//     quad reduce-scatter -> lane kq owns gate kq -> OWN-gate activation
//     (1 exp + 1 rcp, constants hoisted) -> 4 DPP quad-broadcasts -> c/h.
//     P-row prefetch: x via LDS, row base via readfirstlane (SALU math,
//     single saddr+voffset global load).
//   tid in [448,484): em tag projection (quad all-reduce).
// ONE barrier per step.
// ---------------------------------------------------------------------------
__global__ __attribute__((amdgpu_flat_work_group_size(512, 512), amdgpu_waves_per_eu(4, 4)))
void lstm_kernel(
    const int* __restrict__ x,
    const float* __restrict__ Pf, const float* __restrict__ Pb,
    const float* __restrict__ Whh_f, const float* __restrict__ Whh_b,
    const float* __restrict__ Wlin,
    float* __restrict__ em_f, float* __restrict__ em_b)
{
  __shared__ __align__(16) float h_lds[2][104];
  __shared__ int   x_lds[S];
  __shared__ float em_lds[S * T];

  int tid = threadIdx.x;
  int dir = blockIdx.x & 1;
  int b   = blockIdx.x >> 1;

  const float* P   = dir ? Pb : Pf;
  const float* Whh = dir ? Whh_b : Whh_f;
  float*       em  = dir ? em_b : em_f;

  bool is_mv = (tid < 400);
  int  og = tid >> 2, kq = tid & 3;
  bool lo2  = (kq < 2);
  bool oddl = (kq & 1);

  bool is_em = (tid >= 448 && tid < 448 + 4 * T);
  int  et = tid - 448;
  int  etag = et >> 2, ekq = et & 3;

  // hoisted own-gate activation constants (gate 2 = tanh, others = sigmoid)
  float mexp = (kq == 2) ? -2.f : -1.f;
  float sA   = (kq == 2) ?  2.f :  1.f;
  float sB   = (kq == 2) ? -1.f :  0.f;

  // weights: 4 gates x (24 quarter + 1 remainder) = 100 floats
  v2f  w2[4][12];
  float wr[4];
  if (is_mv) {
#pragma unroll
    for (int q = 0; q < 4; q++) {
      const float* row = &Whh[(size_t)(q * 100 + og) * 100];
#pragma unroll
      for (int i = 0; i < 6; i++) {
        float4 t4 = *(const float4*)&row[24 * kq + 4 * i];
        w2[q][2 * i]     = (v2f){t4.x, t4.y};
        w2[q][2 * i + 1] = (v2f){t4.z, t4.w};
      }
      wr[q] = row[96 + kq];
    }
  } else if (is_em) {
    const float* row = &Wlin[etag * (2 * H) + dir * H];
#pragma unroll
    for (int i = 0; i < 6; i++) {
      float4 t4 = *(const float4*)&row[24 * ekq + 4 * i];
      w2[0][2 * i]     = (v2f){t4.x, t4.y};
      w2[0][2 * i + 1] = (v2f){t4.z, t4.w};
    }
    wr[0] = row[96 + ekq];
  }

  for (int i = tid; i < 208; i += 512) ((float*)h_lds)[i] = 0.f;
  for (int i = tid; i < S; i += 512) x_lds[i] = x[(size_t)b * S + i];
  float c = 0.f;
  float pre = 0.f;
  if (is_mv) {
    int tt0 = dir ? (S - 1) : 0;
    pre = P[(size_t)x[(size_t)b * S + tt0] * 400 + tid];
  }
  int prev_tt = 0;
  __syncthreads();

  auto step = [&](int bufc, int t) {
    int tt = dir ? (S - 1 - t) : t;
    if (is_mv) {
      float prv = pre;
      if (t + 1 < S) {                      // register prefetch, SGPR base
        int ttn = dir ? (S - 2 - t) : (t + 1);
        int xv = x_lds[ttn];                // wave-uniform
        unsigned sxv = __builtin_amdgcn_readfirstlane(xv);
        const float* rowp = P + (size_t)sxv * 400;
        pre = rowp[tid];
      }
      const float* hq = &h_lds[bufc][24 * kq];
      v2f a0 = {0.f, 0.f}, a1 = {0.f, 0.f}, a2 = {0.f, 0.f}, a3 = {0.f, 0.f};
#pragma unroll
      for (int i = 0; i < 6; i++) {
        float4 h4 = *(const float4*)&hq[4 * i];
        v2f hlo = {h4.x, h4.y}, hhi = {h4.z, h4.w};
        a0 = __builtin_elementwise_fma(w2[0][2 * i], hlo, a0);
        a0 = __builtin_elementwise_fma(w2[0][2 * i + 1], hhi, a0);
        a1 = __builtin_elementwise_fma(w2[1][2 * i], hlo, a1);
        a1 = __builtin_elementwise_fma(w2[1][2 * i + 1], hhi, a1);
        a2 = __builtin_elementwise_fma(w2[2][2 * i], hlo, a2);
        a2 = __builtin_elementwise_fma(w2[2][2 * i + 1], hhi, a2);
        a3 = __builtin_elementwise_fma(w2[3][2 * i], hlo, a3);
        a3 = __builtin_elementwise_fma(w2[3][2 * i + 1], hhi, a3);
      }
      float hr = h_lds[bufc][96 + kq];
      float p0 = fmaf(wr[0], hr, a0.x + a0.y);
      float p1 = fmaf(wr[1], hr, a1.x + a1.y);
      float p2 = fmaf(wr[2], hr, a2.x + a2.y);
      float p3 = fmaf(wr[3], hr, a3.x + a3.y);

      // DPP quad reduce-scatter: lane kq ends with full sum of gate kq
      float u  = lo2 ? p2 : p0;
      float v  = lo2 ? p3 : p1;
      float ru = dpp_mov<0x4E>(u);          // quad_perm [2,3,0,1]
      float rv = dpp_mov<0x4E>(v);
      float A  = (lo2 ? p0 : p2) + ru;
      float Bv = (lo2 ? p1 : p3) + rv;
      float wv = oddl ? A : Bv;
      float rw = dpp_mov<0xB1>(wv);         // quad_perm [1,0,3,2]
      float g  = (oddl ? Bv : A) + rw + prv;

      // own-gate activation
      float e   = __expf(mexp * g);
      float act = fmaf(sA, fast_rcp(1.f + e), sB);

      // broadcast each quad lane's activation
      float gi = dpp_mov<0x00>(act);
      float gf = dpp_mov<0x55>(act);
      float tg = dpp_mov<0xAA>(act);
      float go = dpp_mov<0xFF>(act);

      c = fmaf(gf, c, gi * tg);
      float th = fmaf(2.f, fast_rcp(1.f + __expf(-2.f * c)), -1.f);
      if (kq == 0) h_lds[bufc ^ 1][og] = go * th;
    } else if (is_em && t > 0) {
      const float* hq = &h_lds[bufc][24 * ekq];
      v2f a = {0.f, 0.f};
#pragma unroll
      for (int i = 0; i < 6; i++) {
        float4 h4 = *(const float4*)&hq[4 * i];
        a = __builtin_elementwise_fma(w2[0][2 * i], (v2f){h4.x, h4.y}, a);
        a = __builtin_elementwise_fma(w2[0][2 * i + 1], (v2f){h4.z, h4.w}, a);
      }
      float hr = h_lds[bufc][96 + ekq];
      float p = fmaf(wr[0], hr, a.x + a.y);
      p += dpp_mov<0xB1>(p);
      p += dpp_mov<0x4E>(p);
      if (ekq == 0) em_lds[prev_tt * T + etag] = p;
    }
    __syncthreads();
    prev_tt = tt;
  };

  for (int t = 0; t < S; t += 2) {
    step(0, t);
    step(1, t + 1);
  }

  if (is_em) {   // final step's projection (h(S-1) in h_lds[0])
    const float* hq = &h_lds[0][24 * ekq];
    v2f a = {0.f, 0.f};
#pragma unroll
    for (int i = 0; i < 6; i++) {
      float4 h4 = *(const float4*)&hq[4 * i];
      a = __builtin_elementwise_fma(w2[0][2 * i], (v2f){h4.x, h4.y}, a);
      a = __builtin_elementwise_fma(w2[0][2 * i + 1], (v2f){h4.z, h4.w}, a);
    }
    float hr = h_lds[0][96 + ekq];
    float p = fmaf(wr[0], hr, a.x + a.y);
    p += dpp_mov<0xB1>(p);
    p += dpp_mov<0x4E>(p);
    if (ekq == 0) em_lds[prev_tt * T + etag] = p;
  }
  __syncthreads();

  float* dst = em + (size_t)b * S * T;
  for (int i = tid; i < S * T; i += 512) dst[i] = em_lds[i];
}

// ---------------------------------------------------------------------------
// Kernel 3: Viterbi. Bulk-preload em_f+em_b+blin combined into LDS (stride
// 12), then the 511-step DP runs with zero global traffic and no scratch.
// One wave per row; lane = cur tag; strict '>' = jnp.argmax tie-break.
// ---------------------------------------------------------------------------
__global__ __launch_bounds__(64) void viterbi_kernel(
    const float* __restrict__ em_f, const float* __restrict__ em_b,
    const float* __restrict__ blin, const float* __restrict__ start,
    const float* __restrict__ trans, const float* __restrict__ endv,
    float* __restrict__ out)
{
  __shared__ float ev[S * 12];         // 24.6 KB combined emissions
  __shared__ unsigned char bp[S * T];  // 4.6 KB backpointers
  int b = blockIdx.x;
  int lane = threadIdx.x;
  bool act = (lane < T);
  int tag = act ? lane : 0;

  const float* ef = em_f + (size_t)b * S * T;
  const float* eb = em_b + (size_t)b * S * T;
  for (int i = lane; i < S * T; i += 64) {
    int t = i / 9, tg = i - t * 9;
    ev[t * 12 + tg] = ef[i] + eb[i] + blin[tg];
  }
  __syncthreads();

  float tc[T] = {};
  float en = 0.f;
  float score = -1e30f;
  if (act) {
    for (int p = 0; p < T; p++) tc[p] = trans[p * T + tag];
    en = endv[tag];
    score = start[tag] + ev[tag];
  }

  for (int t = 1; t < S; t++) {
    float emv = act ? ev[t * 12 + tag] : 0.f;
    float best = -1e30f; int bestp = 0;
#pragma unroll
    for (int p = 0; p < T; p++) {
      float sp = __shfl(score, p);
      float cand = sp + tc[p];
      if (cand > best) { best = cand; bestp = p; }
    }
    if (act) {
      score = best + emv;
      bp[t * T + tag] = (unsigned char)bestp;
    }
  }
  if (act) score += en;
  __syncthreads();

  float bs = -1e30f; int last = 0;
#pragma unroll
  for (int p = 0; p < T; p++) {
    float sp = __shfl(score, p);
    if (sp > bs) { bs = sp; last = p; }
  }

  if (lane == 0) {
    out[(size_t)B * S + b] = bs;
    int cur = last;
    out[(size_t)b * S + (S - 1)] = (float)cur;
    for (int t = S - 1; t >= 1; t--) {
      cur = bp[t * T + cur];
      out[(size_t)b * S + (t - 1)] = (float)cur;
    }
  }
}

// ---------------------------------------------------------------------------
extern "C" void kernel_launch(void* const* d_in, const int* in_sizes, int n_in,
                              void* d_out, int out_size, void* d_ws, size_t ws_size,
                              hipStream_t stream)
{
  const int*   x     = (const int*)d_in[0];
  const float* embed = (const float*)d_in[2];
  const float* Wih_f = (const float*)d_in[3];
  const float* Whh_f = (const float*)d_in[4];
  const float* b_f   = (const float*)d_in[5];
  const float* Wih_b = (const float*)d_in[6];
  const float* Whh_b = (const float*)d_in[7];
  const float* b_b   = (const float*)d_in[8];
  const float* Wlin  = (const float*)d_in[9];
  const float* blin  = (const float*)d_in[10];
  const float* start = (const float*)d_in[11];
  const float* trans = (const float*)d_in[12];
  const float* endv  = (const float*)d_in[13];
  float* out = (float*)d_out;

  char* ws = (char*)d_ws;
  float* Pf   = (float*)ws;  ws += (size_t)V * 400 * sizeof(float);
  float* Pb   = (float*)ws;  ws += (size_t)V * 400 * sizeof(float);
  float* emf  = (float*)ws;  ws += (size_t)B * S * T * sizeof(float);
  float* emb_ = (float*)ws;  ws += (size_t)B * S * T * sizeof(float);

  precompute_P<<<dim3(13, 469), 256, 0, stream>>>(embed, Wih_f, b_f, Wih_b, b_b, Pf, Pb);
  lstm_kernel<<<dim3(512), 512, 0, stream>>>(x, Pf, Pb, Whh_f, Whh_b, Wlin, emf, emb_);
  viterbi_kernel<<<dim3(256), 64, 0, stream>>>(emf, emb_, blin, start, trans, endv, out);
}